// Round 11
// baseline (636.319 us; speedup 1.0000x reference)
//
#include <hip/hip_runtime.h>
#include <hip/hip_bf16.h>
#include <stdint.h>

typedef __attribute__((ext_vector_type(8))) short bf16x8;
typedef __attribute__((ext_vector_type(4))) float f32x4;
typedef __attribute__((ext_vector_type(8))) unsigned short u16x8;

#define BM 256
#define BN 256
#define BKT 32
#define ABYTES (BM * BKT * 2)        // 16384
#define BBYTES (BN * BKT * 2)        // 16384
#define BUFBYTES (ABYTES + BBYTES)   // 32768
#define NBUF 4                       // 128 KB ring, depth-3 staging

// ---- MXFP8 quant-dequant to bf16 (verified r1/r5-r10: absmax 0.03125) ------
__device__ __forceinline__ float mx_qd_elem(float x, int e) {
    float xs = ldexpf(x, -e);
    xs = fminf(448.f, fmaxf(-448.f, xs));
    float a = fabsf(xs);
    float r;
    if (a < 0.015625f) {                  // below 2^-6: e4m3 subnormal, quantum 2^-9
        r = ldexpf(rintf(ldexpf(a, 9)), -9);
    } else {                              // normal: quantum 2^(E-3)
        int E = (int)((__float_as_uint(a) >> 23) & 0xFF) - 127;
        r = ldexpf(rintf(ldexpf(a, 3 - E)), E - 3);
    }
    r = copysignf(r, xs);
    return ldexpf(r, e);
}

__global__ __launch_bounds__(256) void mx_quant_bf16(
    const float* __restrict__ in, uint16_t* __restrict__ out, int nblk) {
    int t = blockIdx.x * 256 + threadIdx.x;
    if (t >= nblk) return;
    const float4* p = (const float4*)(in + (size_t)t * 32);
    float v[32];
#pragma unroll
    for (int i = 0; i < 8; ++i) {
        float4 fv = p[i];
        v[4 * i + 0] = fv.x; v[4 * i + 1] = fv.y;
        v[4 * i + 2] = fv.z; v[4 * i + 3] = fv.w;
    }
    float amax = 0.f;
#pragma unroll
    for (int i = 0; i < 32; ++i) amax = fmaxf(amax, fabsf(v[i]));
    amax = fmaxf(amax, 1.17549435e-38f);
    int e = (int)((__float_as_uint(amax) >> 23) & 0xFF) - 127 - 8;

    unsigned short res[32];
#pragma unroll
    for (int i = 0; i < 32; ++i) {
        float d = mx_qd_elem(v[i], e);
        res[i] = (unsigned short)(__float_as_uint(d) >> 16);
    }
    u16x8* o = (u16x8*)(out + (size_t)t * 32);
#pragma unroll
    for (int j = 0; j < 4; ++j) {
        u16x8 pack;
#pragma unroll
        for (int i = 0; i < 8; ++i) pack[i] = res[8 * j + i];
        o[j] = pack;
    }
}

// ---- 256x256 cross-tile-pipelined bf16 GEMM: C = A * B^T + bias ------------
// 8 waves (2M x 4N), acc[8][4]; BK=32; 4-buf ring; depth-3 staging.
// Fragments E(t)={bA,aLo} read ONE TILE AHEAD (during tile t-1's cluster 1,
// alternating reg sets); H(t)={aHi} read in-tile, drains under cluster 1.
// All waits counted (lgkm 4/8, vmcnt 4); 0 only in the tail ledger.
#define GLOAD(srcp, ldsoff)                                                     \
    __builtin_amdgcn_global_load_lds(                                           \
        (const __attribute__((address_space(1))) void*)(srcp),                  \
        (__attribute__((address_space(3))) void*)&lds[ldsoff], 16, 0, 0)

__global__ __launch_bounds__(512, 2) void gemm_p3_bf16(
    const uint16_t* __restrict__ A, const uint16_t* __restrict__ B,
    const float* __restrict__ bias, float* __restrict__ C,
    int Nrows, int K, int O) {
    __shared__ __align__(16) uint8_t lds[NBUF * BUFBYTES];   // 128 KB

    const int tid  = threadIdx.x;
    const int lane = tid & 63;
    const int w    = tid >> 6;
    const int f    = lane & 15, g = lane >> 4;
    const int wm   = w >> 2,    wn = w & 3;     // 2M x 4N

    // T1: bijective XCD swizzle (nwg = 1024, %8 == 0)
    const int nwg  = gridDim.x * gridDim.y;
    const int flat = blockIdx.y * gridDim.x + blockIdx.x;
    const int swz  = (flat & 7) * (nwg >> 3) + (flat >> 3);
    const int bx   = swz % gridDim.x, by = swz / gridDim.x;
    const int rowBase = by * BM, colBase = bx * BN;

    // staging (r10-verified): linear LDS dest; source col slot-swizzled
    const int srow = tid >> 2;
    const int ssc  = ((tid & 3) ^ ((srow >> 1) & 3)) * 16;
    const size_t K2 = (size_t)K * 2;
    const uint8_t* gA0 = (const uint8_t*)A + (size_t)(rowBase + srow) * K2 + ssc;
    const uint8_t* gA1 = (const uint8_t*)A + (size_t)(rowBase + 128 + srow) * K2 + ssc;
    const uint8_t* gB0 = (const uint8_t*)B + (size_t)(colBase + srow) * K2 + ssc;
    const uint8_t* gB1 = (const uint8_t*)B + (size_t)(colBase + 128 + srow) * K2 + ssc;
    const int sld = tid * 16;
#define STAGE(t) do {                                                           \
        const int _buf = ((t) & 3) * BUFBYTES;                                  \
        const size_t _kb = (size_t)(t) * (BKT * 2);                             \
        GLOAD(gA0 + _kb, _buf + sld);                                           \
        GLOAD(gA1 + _kb, _buf + 8192 + sld);                                    \
        GLOAD(gB0 + _kb, _buf + ABYTES + sld);                                  \
        GLOAD(gB1 + _kb, _buf + ABYTES + 8192 + sld);                           \
    } while (0)

    // frag-read offsets (r10-verified slot swizzle, 0 conflicts)
    int aoff[8], boff[4];
#pragma unroll
    for (int m = 0; m < 8; ++m) {
        int r = wm * 128 + m * 16 + f;
        aoff[m] = r * 64 + ((g ^ ((r >> 1) & 3)) * 16);
    }
#pragma unroll
    for (int n = 0; n < 4; ++n) {
        int r = wn * 64 + n * 16 + f;
        boff[n] = ABYTES + r * 64 + ((g ^ ((r >> 1) & 3)) * 16);
    }

    f32x4 acc[8][4];
#pragma unroll
    for (int m = 0; m < 8; ++m)
#pragma unroll
        for (int n = 0; n < 4; ++n)
#pragma unroll
            for (int j = 0; j < 4; ++j) acc[m][n][j] = 0.f;

    const int nt = K / BKT;   // 128 (even; unrolled x2)

#define WAITL(N) do {                                                           \
        asm volatile("s_waitcnt lgkmcnt(" #N ")" ::: "memory");                 \
        __builtin_amdgcn_sched_barrier(0);                                      \
    } while (0)
#define MFMA_C(MB, AF, BF) do {                                                 \
        __builtin_amdgcn_s_setprio(1);                                          \
        _Pragma("unroll") for (int _m = 0; _m < 4; ++_m)                        \
        _Pragma("unroll") for (int _n = 0; _n < 4; ++_n)                        \
            acc[(MB) + _m][_n] = __builtin_amdgcn_mfma_f32_16x16x32_bf16(       \
                AF[_m], BF[_n], acc[(MB) + _m][_n], 0, 0, 0);                   \
        __builtin_amdgcn_s_setprio(0);                                          \
    } while (0)

    bf16x8 bA0[4], aLo0[4], bA1[4], aLo1[4], aHi[4];

    // Per-tile ledger (per thread):
    //  step1 H(t) [4 ds] ; WAITL(4) retires E(t) (8, issued last tile)
    //  issue E(t+1) [8 ds from buf t+1, complete since end-of-(t-1)]
    //  MFMA c1 ; WAITL(8) retires H(t) (E(t+1) stays) ; STAGE(t+3) [4 vm]
    //  MFMA c2 ; vmcnt(4) retires stage(t+2) ; barrier
#define TILE_BODY(t, bAc, aLoc, bAn, aLon) do {                                 \
        const int bb = ((t) & 3) * BUFBYTES;                                    \
        _Pragma("unroll") for (int _m = 0; _m < 4; ++_m)                        \
            aHi[_m] = *(const bf16x8*)&lds[bb + aoff[4 + _m]];                  \
        WAITL(4);                                                               \
        if ((t) + 1 < nt) {                                                     \
            const int bb1 = (((t) + 1) & 3) * BUFBYTES;                         \
            _Pragma("unroll") for (int _n = 0; _n < 4; ++_n)                    \
                bAn[_n] = *(const bf16x8*)&lds[bb1 + boff[_n]];                 \
            _Pragma("unroll") for (int _m = 0; _m < 4; ++_m)                    \
                aLon[_m] = *(const bf16x8*)&lds[bb1 + aoff[_m]];                \
        }                                                                       \
        MFMA_C(0, aLoc, bAc);                                                   \
        if ((t) + 1 < nt) WAITL(8); else WAITL(0);                              \
        if ((t) + 3 < nt) STAGE((t) + 3);                                       \
        MFMA_C(4, aHi, bAc);                                                    \
        if ((t) + 3 < nt) asm volatile("s_waitcnt vmcnt(4)" ::: "memory");      \
        else              asm volatile("s_waitcnt vmcnt(0)" ::: "memory");      \
        __builtin_amdgcn_sched_barrier(0);                                      \
        __builtin_amdgcn_s_barrier();                                           \
        __builtin_amdgcn_sched_barrier(0);                                      \
    } while (0)

    // prologue: stage 0,1,2; retire 0,1 (vmcnt(4)); publish; pre-read E(0)
    STAGE(0); STAGE(1); STAGE(2);
    asm volatile("s_waitcnt vmcnt(4)" ::: "memory");
    __builtin_amdgcn_sched_barrier(0);
    __builtin_amdgcn_s_barrier();
    __builtin_amdgcn_sched_barrier(0);
#pragma unroll
    for (int n = 0; n < 4; ++n) bA0[n] = *(const bf16x8*)&lds[boff[n]];
#pragma unroll
    for (int m = 0; m < 4; ++m) aLo0[m] = *(const bf16x8*)&lds[aoff[m]];

    for (int tt = 0; tt < nt; tt += 2) {
        TILE_BODY(tt,     bA0, aLo0, bA1, aLo1);
        TILE_BODY(tt + 1, bA1, aLo1, bA0, aLo0);
    }
#undef STAGE
#undef WAITL
#undef MFMA_C
#undef TILE_BODY

    // epilogue: C/D layout col=lane&15, row=(lane>>4)*4+j (r1/r5-r10 verified)
    const int qr = g * 4;
#pragma unroll
    for (int n = 0; n < 4; ++n) {
        int col = colBase + wn * 64 + n * 16 + f;
        float bv = bias[col];
#pragma unroll
        for (int m = 0; m < 8; ++m) {
            int r0 = rowBase + wm * 128 + m * 16 + qr;
#pragma unroll
            for (int j = 0; j < 4; ++j)
                C[(size_t)(r0 + j) * O + col] = acc[m][n][j] + bv;
        }
    }
}

extern "C" void kernel_launch(void* const* d_in, const int* in_sizes, int n_in,
                              void* d_out, int out_size, void* d_ws, size_t ws_size,
                              hipStream_t stream) {
    const float* x    = (const float*)d_in[0];
    const float* wgt  = (const float*)d_in[1];
    const float* bias = (const float*)d_in[2];
    float* out = (float*)d_out;

    const int D_OUT = in_sizes[2];             // 4096
    const int D_IN  = in_sizes[1] / D_OUT;     // 4096
    const int NROWS = in_sizes[0] / D_IN;      // 16384

    uint16_t* xq = (uint16_t*)d_ws;                     // 128 MB
    uint16_t* wq = xq + (size_t)NROWS * D_IN;           //  32 MB

    int nblkx = NROWS * (D_IN / 32);
    int nblkw = D_OUT * (D_IN / 32);
    mx_quant_bf16<<<dim3((nblkx + 255) / 256), dim3(256), 0, stream>>>(x, xq, nblkx);
    mx_quant_bf16<<<dim3((nblkw + 255) / 256), dim3(256), 0, stream>>>(wgt, wq, nblkw);

    dim3 grid(D_OUT / BN, NROWS / BM);   // (16, 64) = 1024 blocks
    gemm_p3_bf16<<<grid, dim3(512), 0, stream>>>(xq, wq, bias, out,
                                                 NROWS, D_IN, D_OUT);
}

// Round 12
// 596.063 us; speedup vs baseline: 1.0675x; 1.0675x over previous
//
#include <hip/hip_runtime.h>
#include <hip/hip_bf16.h>
#include <stdint.h>

typedef __attribute__((ext_vector_type(8))) short bf16x8;
typedef __attribute__((ext_vector_type(4))) float f32x4;
typedef __attribute__((ext_vector_type(8))) unsigned short u16x8;

#define BM 256
#define BN 256
#define BKT 64
#define ABYTES (BM * BKT * 2)        // 32768
#define BBYTES (BN * BKT * 2)        // 32768
#define BUFBYTES (ABYTES + BBYTES)   // 65536; 2 buffers = 128 KB LDS

// ---- MXFP8 quant-dequant to bf16 (verified r1/r5-r11: absmax 0.03125) ------
__device__ __forceinline__ float mx_qd_elem(float x, int e) {
    float xs = ldexpf(x, -e);
    xs = fminf(448.f, fmaxf(-448.f, xs));
    float a = fabsf(xs);
    float r;
    if (a < 0.015625f) {                  // below 2^-6: e4m3 subnormal, quantum 2^-9
        r = ldexpf(rintf(ldexpf(a, 9)), -9);
    } else {                              // normal: quantum 2^(E-3)
        int E = (int)((__float_as_uint(a) >> 23) & 0xFF) - 127;
        r = ldexpf(rintf(ldexpf(a, 3 - E)), E - 3);
    }
    r = copysignf(r, xs);
    return ldexpf(r, e);
}

__global__ __launch_bounds__(256) void mx_quant_bf16(
    const float* __restrict__ in, uint16_t* __restrict__ out, int nblk) {
    int t = blockIdx.x * 256 + threadIdx.x;
    if (t >= nblk) return;
    const float4* p = (const float4*)(in + (size_t)t * 32);
    float v[32];
#pragma unroll
    for (int i = 0; i < 8; ++i) {
        float4 fv = p[i];
        v[4 * i + 0] = fv.x; v[4 * i + 1] = fv.y;
        v[4 * i + 2] = fv.z; v[4 * i + 3] = fv.w;
    }
    float amax = 0.f;
#pragma unroll
    for (int i = 0; i < 32; ++i) amax = fmaxf(amax, fabsf(v[i]));
    amax = fmaxf(amax, 1.17549435e-38f);
    int e = (int)((__float_as_uint(amax) >> 23) & 0xFF) - 127 - 8;

    unsigned short res[32];
#pragma unroll
    for (int i = 0; i < 32; ++i) {
        float d = mx_qd_elem(v[i], e);
        res[i] = (unsigned short)(__float_as_uint(d) >> 16);
    }
    u16x8* o = (u16x8*)(out + (size_t)t * 32);
#pragma unroll
    for (int j = 0; j < 4; ++j) {
        u16x8 pack;
#pragma unroll
        for (int i = 0; i < 8; ++i) pack[i] = res[8 * j + i];
        o[j] = pack;
    }
}

// ---- 256x256 chunk-pipelined bf16 GEMM (r8 schedule) + L2-residency swizzle
// XCD k owns bx in {2k,2k+1}, sweeps by 0..63 (snake): the 2MB B-panel per
// column stays L2-resident for its whole sweep -> B L3-traffic 2GB -> 256MB.
#define GLOAD(srcp, ldsoff)                                                     \
    __builtin_amdgcn_global_load_lds(                                           \
        (const __attribute__((address_space(1))) void*)(srcp),                  \
        (__attribute__((address_space(3))) void*)&lds[ldsoff], 16, 0, 0)

__global__ __launch_bounds__(512, 2) void gemm_l2_bf16(
    const uint16_t* __restrict__ A, const uint16_t* __restrict__ B,
    const float* __restrict__ bias, float* __restrict__ C,
    int Nrows, int K, int O) {
    __shared__ __align__(16) uint8_t lds[2 * BUFBYTES];   // 128 KB

    const int tid  = threadIdx.x;
    const int lane = tid & 63;
    const int w    = tid >> 6;
    const int f    = lane & 15, g = lane >> 4;
    const int wm   = w >> 2,    wn = w & 3;     // 2M x 4N

    // column-chunked XCD swizzle (bijective; HW round-robins blockIdx%8 -> XCD)
    const int flat = blockIdx.y * gridDim.x + blockIdx.x;   // 0..1023
    const int xcd  = flat & 7;
    const int loc  = flat >> 3;                 // 0..127 within XCD
    const int bxl  = loc >> 6;                  // column 0/1 within XCD band
    const int byl  = loc & 63;
    const int by   = bxl ? (63 - byl) : byl;    // snake: A-panel reuse at turn
    const int bx   = xcd * 2 + bxl;
    const int rowBase = by * BM, colBase = bx * BN;

    // staging: round = 64 rows x 128 B; thread covers 16 B. linear LDS dest
    // (rule 21); SOURCE col pre-inverse-swizzled (r5/r6-verified formulas).
    const int sri = tid >> 3;
    const int ssc = ((tid & 7) * 16) ^ ((sri & 7) << 4);
    const int sld = tid * 16;
    const size_t K2 = (size_t)K * 2;
    const uint8_t* gAr[4]; const uint8_t* gBr[4];
#pragma unroll
    for (int r = 0; r < 4; ++r) {
        gAr[r] = (const uint8_t*)A + (size_t)(rowBase + r * 64 + sri) * K2 + ssc;
        gBr[r] = (const uint8_t*)B + (size_t)(colBase + r * 64 + sri) * K2 + ssc;
    }
#define STAGE(t) do {                                                           \
        const int _buf = ((t) & 1) * BUFBYTES;                                  \
        const size_t _kb = (size_t)(t) * (BKT * 2);                             \
        _Pragma("unroll")                                                       \
        for (int _i = 0; _i < 4; ++_i)                                          \
            GLOAD(gAr[_i] + _kb, _buf + _i * 8192 + sld);                       \
        _Pragma("unroll")                                                       \
        for (int _i = 0; _i < 4; ++_i)                                          \
            GLOAD(gBr[_i] + _kb, _buf + ABYTES + _i * 8192 + sld);              \
    } while (0)

    // swizzled frag-read offsets: LDS[r][c] = G[r][c ^ ((r&7)<<4)]
    int aoff[8][2], boff[4][2];
#pragma unroll
    for (int kk = 0; kk < 2; ++kk) {
        const int colb = (kk * 64 + g * 16) ^ ((f & 7) << 4);
#pragma unroll
        for (int m = 0; m < 8; ++m)
            aoff[m][kk] = (wm * 128 + m * 16 + f) * 128 + colb;
#pragma unroll
        for (int n = 0; n < 4; ++n)
            boff[n][kk] = ABYTES + (wn * 64 + n * 16 + f) * 128 + colb;
    }

    f32x4 acc[8][4];
#pragma unroll
    for (int m = 0; m < 8; ++m)
#pragma unroll
        for (int n = 0; n < 4; ++n)
#pragma unroll
            for (int j = 0; j < 4; ++j) acc[m][n][j] = 0.f;

    const int nt = K / BKT;   // 64

#define WAITL(N) do {                                                           \
        asm volatile("s_waitcnt lgkmcnt(" #N ")" ::: "memory");                 \
        __builtin_amdgcn_sched_barrier(0);                                      \
    } while (0)
#define MFMA_C(MB, AF, BF) do {                                                 \
        __builtin_amdgcn_s_setprio(1);                                          \
        _Pragma("unroll") for (int _m = 0; _m < 4; ++_m)                        \
        _Pragma("unroll") for (int _n = 0; _n < 4; ++_n)                        \
            acc[(MB) + _m][_n] = __builtin_amdgcn_mfma_f32_16x16x32_bf16(       \
                AF[_m], BF[_n], acc[(MB) + _m][_n], 0, 0, 0);                   \
        __builtin_amdgcn_s_setprio(0);                                          \
    } while (0)

    // prologue: stage tile 0, drain, publish
    STAGE(0);
    asm volatile("s_waitcnt vmcnt(0)" ::: "memory");
    __builtin_amdgcn_sched_barrier(0);
    __builtin_amdgcn_s_barrier();
    __builtin_amdgcn_sched_barrier(0);

    for (int t = 0; t < nt; ++t) {
        const int bb = (t & 1) * BUFBYTES;
        const bool pf = (t + 1) < nt;
        bf16x8 bA[4], bB[4], aLo[4], aHi[4], aLo1[4], aHi1[4];

        // c0 (8 reads): B kk0 + A m0-3 kk0
#pragma unroll
        for (int n = 0; n < 4; ++n) bA[n] = *(const bf16x8*)&lds[bb + boff[n][0]];
#pragma unroll
        for (int m = 0; m < 4; ++m) aLo[m] = *(const bf16x8*)&lds[bb + aoff[m][0]];
        // c1 (4 reads): A m4-7 kk0
#pragma unroll
        for (int m = 0; m < 4; ++m) aHi[m] = *(const bf16x8*)&lds[bb + aoff[4 + m][0]];
        if (pf) STAGE(t + 1);            // gload issue overlaps c0 drain
        WAITL(4);                        // c0 done (c1's 4 outstanding)
        MFMA_C(0, aLo, bA);              // cluster 1; c1 drains under it
        // c2 (8 reads): B kk1 + A m0-3 kk1
#pragma unroll
        for (int n = 0; n < 4; ++n) bB[n] = *(const bf16x8*)&lds[bb + boff[n][1]];
#pragma unroll
        for (int m = 0; m < 4; ++m) aLo1[m] = *(const bf16x8*)&lds[bb + aoff[m][1]];
        WAITL(8);                        // c1 done (c2's 8 outstanding)
        MFMA_C(4, aHi, bA);              // cluster 2; c2 drains under it
        // c3 (4 reads): A m4-7 kk1
#pragma unroll
        for (int m = 0; m < 4; ++m) aHi1[m] = *(const bf16x8*)&lds[bb + aoff[4 + m][1]];
        WAITL(4);                        // c2 done (c3's 4 outstanding)
        MFMA_C(0, aLo1, bB);             // cluster 3; c3 drains under it
        WAITL(0);                        // c3 done
        MFMA_C(4, aHi1, bB);             // cluster 4
        // publish tile t+1 and release buffers
        asm volatile("s_waitcnt vmcnt(0)" ::: "memory");
        __builtin_amdgcn_sched_barrier(0);
        __builtin_amdgcn_s_barrier();
        __builtin_amdgcn_sched_barrier(0);
    }
#undef STAGE
#undef WAITL
#undef MFMA_C

    // epilogue: C/D layout col=lane&15, row=(lane>>4)*4+j (r1/r5-r11 verified)
    const int qr = g * 4;
#pragma unroll
    for (int n = 0; n < 4; ++n) {
        int col = colBase + wn * 64 + n * 16 + f;
        float bv = bias[col];
#pragma unroll
        for (int m = 0; m < 8; ++m) {
            int r0 = rowBase + wm * 128 + m * 16 + qr;
#pragma unroll
            for (int j = 0; j < 4; ++j)
                C[(size_t)(r0 + j) * O + col] = acc[m][n][j] + bv;
        }
    }
}

extern "C" void kernel_launch(void* const* d_in, const int* in_sizes, int n_in,
                              void* d_out, int out_size, void* d_ws, size_t ws_size,
                              hipStream_t stream) {
    const float* x    = (const float*)d_in[0];
    const float* wgt  = (const float*)d_in[1];
    const float* bias = (const float*)d_in[2];
    float* out = (float*)d_out;

    const int D_OUT = in_sizes[2];             // 4096
    const int D_IN  = in_sizes[1] / D_OUT;     // 4096
    const int NROWS = in_sizes[0] / D_IN;      // 16384

    uint16_t* xq = (uint16_t*)d_ws;                     // 128 MB
    uint16_t* wq = xq + (size_t)NROWS * D_IN;           //  32 MB

    int nblkx = NROWS * (D_IN / 32);
    int nblkw = D_OUT * (D_IN / 32);
    mx_quant_bf16<<<dim3((nblkx + 255) / 256), dim3(256), 0, stream>>>(x, xq, nblkx);
    mx_quant_bf16<<<dim3((nblkw + 255) / 256), dim3(256), 0, stream>>>(wgt, wq, nblkw);

    dim3 grid(D_OUT / BN, NROWS / BM);   // (16, 64) = 1024 blocks
    gemm_l2_bf16<<<grid, dim3(512), 0, stream>>>(xq, wq, bias, out,
                                                 NROWS, D_IN, D_OUT);
}